// Round 9
// baseline (288.762 us; speedup 1.0000x reference)
//
#include <hip/hip_runtime.h>
#include <math.h>

typedef int intx4 __attribute__((ext_vector_type(4)));
typedef int intx8 __attribute__((ext_vector_type(8)));
typedef float floatx16 __attribute__((ext_vector_type(16)));

#define N_ROWS 8192
#define KDIM 1024

// E8M0 scale bytes: 123 -> 2^-4 per side (data pre-scaled by 2^4 each side)
#define SCALE_WORD 0x7B7B7B7B

// order-preserving float->int encoding for atomicMax
__device__ __forceinline__ int fenc(float f) {
  int i = __float_as_int(f);
  return i >= 0 ? i : (i ^ 0x7fffffff);
}
__device__ __forceinline__ float fdec(int e) {
  int b = e >= 0 ? e : (e ^ 0x7fffffff);
  return __int_as_float(b);
}

// One WAVE per row (4 rows/block, no __syncthreads): computes 1/||x|| (fp32),
// writes row normalized*16 as e4m3 via HW cvt, inits the max slot.
__global__ __launch_bounds__(256) void normalize_kernel(
    const float* __restrict__ ex, const float* __restrict__ ey,
    unsigned char* __restrict__ exn, unsigned char* __restrict__ eyn,
    int* __restrict__ rowmax, int* __restrict__ colmax) {
  const int wave = threadIdx.x >> 6, lane = threadIdx.x & 63;
  const int gr = blockIdx.x * 4 + wave;  // 0..16383
  const float* x;
  unsigned char* out;
  int* mslot;
  int row;
  if (gr < N_ROWS) {
    x = ex; out = exn; mslot = rowmax; row = gr;
  } else {
    x = ey; out = eyn; mslot = colmax; row = gr - N_ROWS;
  }
  const float4* xr = (const float4*)(x + (size_t)row * KDIM);
  float4 v[4];
  float ss = 0.f;
#pragma unroll
  for (int j = 0; j < 4; ++j) {
    v[j] = xr[lane + j * 64];  // coalesced
    ss += v[j].x * v[j].x + v[j].y * v[j].y + v[j].z * v[j].z + v[j].w * v[j].w;
  }
#pragma unroll
  for (int off = 32; off > 0; off >>= 1) ss += __shfl_xor(ss, off, 64);
  const float rs = 16.0f * rsqrtf(fmaxf(ss, 1e-24f));  // 2^4 pre-scale
  int* op = (int*)(out + (size_t)row * KDIM);
#pragma unroll
  for (int j = 0; j < 4; ++j) {
    int w = __builtin_amdgcn_cvt_pk_fp8_f32(v[j].x * rs, v[j].y * rs, 0, false);
    w = __builtin_amdgcn_cvt_pk_fp8_f32(v[j].z * rs, v[j].w * rs, w, true);
    op[lane + j * 64] = w;
  }
  if (lane == 0) mslot[row] = (int)0x80000000;  // encoded -inf floor
}

// 128x256 block tile GEMM (A @ B^T, row-major K-contiguous e4m3) with
// mfma_scale_f32_32x32x64_f8f6f4, fused row/col max reduction.
//
// Round-9 change: wave tile 64x64 -> 128x64 (acc[4][2], block 128x256).
// r6 vs r8 showed per-barrier-phase overhead dominates: bigger wave tiles
// raise FLOP/LDS-byte 64 -> 85 (6 frag reads per 8 mfma) and halve per-FLOP
// ds_write traffic; per-CU barrier phases drop to r6's count with ~40% less
// LDS traffic than r6.
//
// Pipeline (verified r6/r8 shape): buffer_load->VGPR->ds_write; only vmcnt
// wait is the ds_write data dependence, placed AFTER compute:
//   LOAD(s+1); COMPUTE(buf s&1); WRITE(buf (s+1)&1); barrier
//
// LDS swizzle (verified r8): 64-B rows, 16-B chunk c of row r at slot
// c ^ ((r>>1)&3) -> bank-group 4*(r&1) + slot covers all 8 groups x 2 lanes
// per quarter-wave. Fragment reads recover true chunk 2h+j (unswizzled), so
// operand bytes at (half,j,b) equal global k = k0+(2h+j)*16+b for BOTH A and
// B -> exact dot-product pairing (absmax 0.0 through r8).
__global__ __launch_bounds__(256) void gemm_max_kernel(
    const unsigned char* __restrict__ A, const unsigned char* __restrict__ B,
    int* __restrict__ rowmax, int* __restrict__ colmax) {
  constexpr int TMA = 128, TNB = 256, BK = 64, K = KDIM;
  constexpr int BUFA = TMA * BK;  // 8 KB
  constexpr int BUFB = TNB * BK;  // 16 KB
  __shared__ __align__(16) unsigned char sA[2 * BUFA];  // 16 KB
  __shared__ __align__(16) unsigned char sB[2 * BUFB];  // 32 KB

  const int bm = blockIdx.x, bn = blockIdx.y;
  const int tid = threadIdx.x;
  const int lane = tid & 63, wave = tid >> 6;
  const int l32 = lane & 31, half = lane >> 5;
  const int fsw = (l32 >> 1) & 3;                 // f(row) = (row>>1)&3
  const int oLo = (((2 * half + 0) ^ fsw) << 4);  // swizzled slot offsets
  const int oHi = (((2 * half + 1) ^ fsw) << 4);

  const char* Ab = (const char*)(A + (size_t)bm * TMA * K);
  const char* Bb = (const char*)(B + (size_t)bn * TNB * K);

  floatx16 acc[4][2] = {};

  // Staging: wave w stages A rows w*32..+31 (2 chunks/lane) and B rows
  // w*64..+63 (4 chunks/lane). Dest is linear lane*16; source chunk is the
  // swizzle-matched one: (lane&3) ^ ((lane>>3)&3) (f(r+16n)==f(r), and the
  // wave-base rows are multiples of 32 so f reduces to (lane>>3)&3).
  const int src_c16 = (((lane & 3) ^ ((lane >> 3) & 3)) << 4);
  const char* gA = Ab + (size_t)(wave * 32 + (lane >> 2)) * K + src_c16;
  const char* gB = Bb + (size_t)(wave * 64 + (lane >> 2)) * K + src_c16;
  unsigned char* wA = sA + wave * 2048 + lane * 16;
  unsigned char* wB = sB + wave * 4096 + lane * 16;

  intx4 pf[6];  // prefetch regs: 2 A-chunks + 4 B-chunks (24 VGPRs)

#define LOADT(k0)                                         \
  do {                                                    \
    pf[0] = *(const intx4*)(gA + (size_t)(k0));           \
    pf[1] = *(const intx4*)(gA + (size_t)(k0) + 16 * K);  \
    pf[2] = *(const intx4*)(gB + (size_t)(k0));           \
    pf[3] = *(const intx4*)(gB + (size_t)(k0) + 16 * K);  \
    pf[4] = *(const intx4*)(gB + (size_t)(k0) + 32 * K);  \
    pf[5] = *(const intx4*)(gB + (size_t)(k0) + 48 * K);  \
  } while (0)

#define WRITET(buf)                                       \
  do {                                                    \
    *(intx4*)(wA + (buf)*BUFA) = pf[0];                   \
    *(intx4*)(wA + (buf)*BUFA + 1024) = pf[1];            \
    *(intx4*)(wB + (buf)*BUFB) = pf[2];                   \
    *(intx4*)(wB + (buf)*BUFB + 1024) = pf[3];            \
    *(intx4*)(wB + (buf)*BUFB + 2048) = pf[4];            \
    *(intx4*)(wB + (buf)*BUFB + 3072) = pf[5];            \
  } while (0)

#define COMPUTE(cur)                                                        \
  do {                                                                      \
    intx8 bF[2];                                                            \
    _Pragma("unroll") for (int ni = 0; ni < 2; ++ni) {                      \
      const unsigned char* bBase =                                          \
          &sB[(cur)*BUFB + (wave * 64 + ni * 32 + l32) * BK];               \
      const intx4 lo = *(const intx4*)(bBase + oLo);                        \
      const intx4 hi = *(const intx4*)(bBase + oHi);                        \
      bF[ni] = __builtin_shufflevector(lo, hi, 0, 1, 2, 3, 4, 5, 6, 7);     \
    }                                                                       \
    _Pragma("unroll") for (int mi = 0; mi < 4; ++mi) {                      \
      const unsigned char* aBase =                                          \
          &sA[(cur)*BUFA + (mi * 32 + l32) * BK];                           \
      const intx4 lo = *(const intx4*)(aBase + oLo);                        \
      const intx4 hi = *(const intx4*)(aBase + oHi);                        \
      const intx8 aFm =                                                     \
          __builtin_shufflevector(lo, hi, 0, 1, 2, 3, 4, 5, 6, 7);          \
      _Pragma("unroll") for (int ni = 0; ni < 2; ++ni)                      \
          acc[mi][ni] = __builtin_amdgcn_mfma_scale_f32_32x32x64_f8f6f4(    \
              aFm, bF[ni], acc[mi][ni], 0, 0, 0, SCALE_WORD, 0,             \
              SCALE_WORD);                                                  \
    }                                                                       \
  } while (0)

  LOADT(0);
  WRITET(0);
  __syncthreads();

  // unroll 1: keeps one pf set live (full unroll would hoist all -> spill)
#pragma unroll 1
  for (int step = 0; step < K / BK - 1; ++step) {
    LOADT((step + 1) * BK);   // in flight across the whole compute phase
    COMPUTE(step & 1);
    WRITET((step + 1) & 1);   // vmcnt wait is data-dependent, post-compute
    __syncthreads();
  }
  COMPUTE((K / BK - 1) & 1);

#undef LOADT
#undef WRITET
#undef COMPUTE

  // 32x32 C/D layout (m74/m101, dtype-independent):
  //   col = lane&31, row = (reg&3) + 8*(reg>>2) + 4*(lane>>5), reg in [0,16)
  // Row maxes: in-lane over ni, shuffle across 32 cols (masks 1..16 stay
  // within a half), l32==0 lanes write.
#pragma unroll
  for (int mi = 0; mi < 4; ++mi) {
#pragma unroll
    for (int reg = 0; reg < 16; ++reg) {
      float v = fmaxf(acc[mi][0][reg], acc[mi][1][reg]);
#pragma unroll
      for (int m = 1; m < 32; m <<= 1) v = fmaxf(v, __shfl_xor(v, m, 64));
      if (l32 == 0) {
        const int grow = bm * TMA + mi * 32 +
                         (reg & 3) + 8 * (reg >> 2) + 4 * half;
        atomicMax(&rowmax[grow], fenc(v));
      }
    }
  }
  // Col maxes: in-lane over mi,reg (64 vals), combine halves via xor 32.
#pragma unroll
  for (int ni = 0; ni < 2; ++ni) {
    float v = -3.402823466e38f;
#pragma unroll
    for (int mi = 0; mi < 4; ++mi)
#pragma unroll
      for (int reg = 0; reg < 16; ++reg) v = fmaxf(v, acc[mi][ni][reg]);
    v = fmaxf(v, __shfl_xor(v, 32, 64));
    if (half == 0) {
      const int gcol = bn * TNB + wave * 64 + ni * 32 + l32;
      atomicMax(&colmax[gcol], fenc(v));
    }
  }
}

__global__ __launch_bounds__(1024) void finalize_kernel(
    const int* __restrict__ rowmax, const int* __restrict__ colmax,
    float* __restrict__ out) {
  const int tid = threadIdx.x;
  float s1 = 0.f, s2 = 0.f;
  for (int i = tid; i < N_ROWS; i += 1024) {
    s1 += 1.0f - fdec(rowmax[i]);
    s2 += 1.0f - fdec(colmax[i]);
  }
#pragma unroll
  for (int off = 32; off > 0; off >>= 1) {
    s1 += __shfl_down(s1, off, 64);
    s2 += __shfl_down(s2, off, 64);
  }
  __shared__ float r1[16], r2[16];
  if ((tid & 63) == 0) {
    r1[tid >> 6] = s1;
    r2[tid >> 6] = s2;
  }
  __syncthreads();
  if (tid == 0) {
    const double SIGMA = 0.3;
    const double H_CONST = 0.5 * log(2.0 * 3.14159265358979323846 * SIGMA * SIGMA) + 0.5;
    const float HS = (float)(H_CONST / SIGMA);
    float a1 = 0.f, a2 = 0.f;
#pragma unroll
    for (int w = 0; w < 16; ++w) {
      a1 += r1[w];
      a2 += r2[w];
    }
    out[0] = HS * a1;
    out[1] = HS * a2;
  }
}

extern "C" void kernel_launch(void* const* d_in, const int* in_sizes, int n_in,
                              void* d_out, int out_size, void* d_ws, size_t ws_size,
                              hipStream_t stream) {
  const float* ex = (const float*)d_in[0];
  const float* ey = (const float*)d_in[1];
  float* out = (float*)d_out;
  char* ws = (char*)d_ws;

  unsigned char* exn = (unsigned char*)ws;                                   // 8 MB
  unsigned char* eyn = (unsigned char*)(ws + (size_t)N_ROWS * KDIM);         // 8 MB
  int* rowmax = (int*)(ws + (size_t)N_ROWS * KDIM * 2);                      // 32 KB
  int* colmax = rowmax + N_ROWS;                                             // 32 KB

  normalize_kernel<<<2 * N_ROWS / 4, 256, 0, stream>>>(ex, ey, exn, eyn, rowmax, colmax);
  gemm_max_kernel<<<dim3(64, 32), 256, 0, stream>>>(exn, eyn, rowmax, colmax);
  finalize_kernel<<<1, 1024, 0, stream>>>(rowmax, colmax, out);
}

// Round 10
// 216.445 us; speedup vs baseline: 1.3341x; 1.3341x over previous
//
#include <hip/hip_runtime.h>
#include <math.h>

typedef int intx4 __attribute__((ext_vector_type(4)));
typedef int intx8 __attribute__((ext_vector_type(8)));
typedef float floatx16 __attribute__((ext_vector_type(16)));

#define N_ROWS 8192
#define KDIM 1024

// E8M0 scale bytes: 123 -> 2^-4 per side (data pre-scaled by 2^4 each side)
#define SCALE_WORD 0x7B7B7B7B

// order-preserving float->int encoding for atomicMax
__device__ __forceinline__ int fenc(float f) {
  int i = __float_as_int(f);
  return i >= 0 ? i : (i ^ 0x7fffffff);
}
__device__ __forceinline__ float fdec(int e) {
  int b = e >= 0 ? e : (e ^ 0x7fffffff);
  return __int_as_float(b);
}

// One WAVE per row (4 rows/block, no __syncthreads): computes 1/||x|| (fp32),
// writes row normalized*16 as e4m3 via HW cvt, inits the max slot.
__global__ __launch_bounds__(256) void normalize_kernel(
    const float* __restrict__ ex, const float* __restrict__ ey,
    unsigned char* __restrict__ exn, unsigned char* __restrict__ eyn,
    int* __restrict__ rowmax, int* __restrict__ colmax) {
  const int wave = threadIdx.x >> 6, lane = threadIdx.x & 63;
  const int gr = blockIdx.x * 4 + wave;  // 0..16383
  const float* x;
  unsigned char* out;
  int* mslot;
  int row;
  if (gr < N_ROWS) {
    x = ex; out = exn; mslot = rowmax; row = gr;
  } else {
    x = ey; out = eyn; mslot = colmax; row = gr - N_ROWS;
  }
  const float4* xr = (const float4*)(x + (size_t)row * KDIM);
  float4 v[4];
  float ss = 0.f;
#pragma unroll
  for (int j = 0; j < 4; ++j) {
    v[j] = xr[lane + j * 64];  // coalesced
    ss += v[j].x * v[j].x + v[j].y * v[j].y + v[j].z * v[j].z + v[j].w * v[j].w;
  }
#pragma unroll
  for (int off = 32; off > 0; off >>= 1) ss += __shfl_xor(ss, off, 64);
  const float rs = 16.0f * rsqrtf(fmaxf(ss, 1e-24f));  // 2^4 pre-scale
  int* op = (int*)(out + (size_t)row * KDIM);
#pragma unroll
  for (int j = 0; j < 4; ++j) {
    int w = __builtin_amdgcn_cvt_pk_fp8_f32(v[j].x * rs, v[j].y * rs, 0, false);
    w = __builtin_amdgcn_cvt_pk_fp8_f32(v[j].z * rs, v[j].w * rs, w, true);
    op[lane + j * 64] = w;
  }
  if (lane == 0) mslot[row] = (int)0x80000000;  // encoded -inf floor
}

// 128x256 block tile GEMM (A @ B^T, row-major K-contiguous e4m3) with
// mfma_scale_f32_32x32x64_f8f6f4, fused row/col max reduction.
//
// Round-10 change: __launch_bounds__(256, 2). Round 9's 128x64 wave tile
// (acc[4][2] = 128 acc regs) compiled at 136 arch VGPRs -> 264 total on the
// unified file -> 1 wave/SIMD -> 1 block/CU -> full latency serialization
// (206 us). The K-loop live set is ~80 regs; forcing arch <= 128 restores
// 2 waves/SIMD (2 blocks/CU). Spill tripwire: WRITE_SIZE (~18 MB clean;
// r4's real spill showed ~987 MB).
//
// Wave tile 128x64 rationale (r9): FLOP/LDS-byte 44 -> 58 vs 64x64, and r6
// is measured AT the LDS-pipe ceiling, so LDS bytes/FLOP is the lever.
//
// Pipeline (verified r6/r8 shape): buffer_load->VGPR->ds_write; only vmcnt
// wait is the ds_write data dependence, placed AFTER compute:
//   LOAD(s+1); COMPUTE(buf s&1); WRITE(buf (s+1)&1); barrier
//
// LDS swizzle (verified r8/r9): 64-B rows, 16-B chunk c of row r at slot
// c ^ ((r>>1)&3) -> bank-group 4*(r&1) + slot covers all 8 groups x 2 lanes
// per quarter-wave. Fragment reads recover true chunk 2h+j, so operand bytes
// at (half,j,b) equal global k = k0+(2h+j)*16+b for BOTH A and B -> exact
// dot-product pairing (absmax 0.0 through r9).
__global__ __launch_bounds__(256, 2) void gemm_max_kernel(
    const unsigned char* __restrict__ A, const unsigned char* __restrict__ B,
    int* __restrict__ rowmax, int* __restrict__ colmax) {
  constexpr int TMA = 128, TNB = 256, BK = 64, K = KDIM;
  constexpr int BUFA = TMA * BK;  // 8 KB
  constexpr int BUFB = TNB * BK;  // 16 KB
  __shared__ __align__(16) unsigned char sA[2 * BUFA];  // 16 KB
  __shared__ __align__(16) unsigned char sB[2 * BUFB];  // 32 KB

  const int bm = blockIdx.x, bn = blockIdx.y;
  const int tid = threadIdx.x;
  const int lane = tid & 63, wave = tid >> 6;
  const int l32 = lane & 31, half = lane >> 5;
  const int fsw = (l32 >> 1) & 3;                 // f(row) = (row>>1)&3
  const int oLo = (((2 * half + 0) ^ fsw) << 4);  // swizzled slot offsets
  const int oHi = (((2 * half + 1) ^ fsw) << 4);

  const char* Ab = (const char*)(A + (size_t)bm * TMA * K);
  const char* Bb = (const char*)(B + (size_t)bn * TNB * K);

  floatx16 acc[4][2] = {};

  // Staging: wave w stages A rows w*32..+31 (2 chunks/lane) and B rows
  // w*64..+63 (4 chunks/lane). Dest is linear lane*16; source chunk is the
  // swizzle-matched one: (lane&3) ^ ((lane>>3)&3) (f(r+16n)==f(r), and the
  // wave-base rows are multiples of 32 so f reduces to (lane>>3)&3).
  const int src_c16 = (((lane & 3) ^ ((lane >> 3) & 3)) << 4);
  const char* gA = Ab + (size_t)(wave * 32 + (lane >> 2)) * K + src_c16;
  const char* gB = Bb + (size_t)(wave * 64 + (lane >> 2)) * K + src_c16;
  unsigned char* wA = sA + wave * 2048 + lane * 16;
  unsigned char* wB = sB + wave * 4096 + lane * 16;

  intx4 pf[6];  // prefetch regs: 2 A-chunks + 4 B-chunks (24 VGPRs)

#define LOADT(k0)                                         \
  do {                                                    \
    pf[0] = *(const intx4*)(gA + (size_t)(k0));           \
    pf[1] = *(const intx4*)(gA + (size_t)(k0) + 16 * K);  \
    pf[2] = *(const intx4*)(gB + (size_t)(k0));           \
    pf[3] = *(const intx4*)(gB + (size_t)(k0) + 16 * K);  \
    pf[4] = *(const intx4*)(gB + (size_t)(k0) + 32 * K);  \
    pf[5] = *(const intx4*)(gB + (size_t)(k0) + 48 * K);  \
  } while (0)

#define WRITET(buf)                                       \
  do {                                                    \
    *(intx4*)(wA + (buf)*BUFA) = pf[0];                   \
    *(intx4*)(wA + (buf)*BUFA + 1024) = pf[1];            \
    *(intx4*)(wB + (buf)*BUFB) = pf[2];                   \
    *(intx4*)(wB + (buf)*BUFB + 1024) = pf[3];            \
    *(intx4*)(wB + (buf)*BUFB + 2048) = pf[4];            \
    *(intx4*)(wB + (buf)*BUFB + 3072) = pf[5];            \
  } while (0)

#define COMPUTE(cur)                                                        \
  do {                                                                      \
    intx8 bF[2];                                                            \
    _Pragma("unroll") for (int ni = 0; ni < 2; ++ni) {                      \
      const unsigned char* bBase =                                          \
          &sB[(cur)*BUFB + (wave * 64 + ni * 32 + l32) * BK];               \
      const intx4 lo = *(const intx4*)(bBase + oLo);                        \
      const intx4 hi = *(const intx4*)(bBase + oHi);                        \
      bF[ni] = __builtin_shufflevector(lo, hi, 0, 1, 2, 3, 4, 5, 6, 7);     \
    }                                                                       \
    _Pragma("unroll") for (int mi = 0; mi < 4; ++mi) {                      \
      const unsigned char* aBase =                                          \
          &sA[(cur)*BUFA + (mi * 32 + l32) * BK];                           \
      const intx4 lo = *(const intx4*)(aBase + oLo);                        \
      const intx4 hi = *(const intx4*)(aBase + oHi);                        \
      const intx8 aFm =                                                     \
          __builtin_shufflevector(lo, hi, 0, 1, 2, 3, 4, 5, 6, 7);          \
      _Pragma("unroll") for (int ni = 0; ni < 2; ++ni)                      \
          acc[mi][ni] = __builtin_amdgcn_mfma_scale_f32_32x32x64_f8f6f4(    \
              aFm, bF[ni], acc[mi][ni], 0, 0, 0, SCALE_WORD, 0,             \
              SCALE_WORD);                                                  \
    }                                                                       \
  } while (0)

  LOADT(0);
  WRITET(0);
  __syncthreads();

  // unroll 1: keeps one pf set live (full unroll would hoist all -> spill)
#pragma unroll 1
  for (int step = 0; step < K / BK - 1; ++step) {
    LOADT((step + 1) * BK);   // in flight across the whole compute phase
    COMPUTE(step & 1);
    WRITET((step + 1) & 1);   // vmcnt wait is data-dependent, post-compute
    __syncthreads();
  }
  COMPUTE((K / BK - 1) & 1);

#undef LOADT
#undef WRITET
#undef COMPUTE

  // 32x32 C/D layout (m74/m101, dtype-independent):
  //   col = lane&31, row = (reg&3) + 8*(reg>>2) + 4*(lane>>5), reg in [0,16)
  // Row maxes: in-lane over ni, shuffle across 32 cols (masks 1..16 stay
  // within a half), l32==0 lanes write.
#pragma unroll
  for (int mi = 0; mi < 4; ++mi) {
#pragma unroll
    for (int reg = 0; reg < 16; ++reg) {
      float v = fmaxf(acc[mi][0][reg], acc[mi][1][reg]);
#pragma unroll
      for (int m = 1; m < 32; m <<= 1) v = fmaxf(v, __shfl_xor(v, m, 64));
      if (l32 == 0) {
        const int grow = bm * TMA + mi * 32 +
                         (reg & 3) + 8 * (reg >> 2) + 4 * half;
        atomicMax(&rowmax[grow], fenc(v));
      }
    }
  }
  // Col maxes: in-lane over mi,reg (64 vals), combine halves via xor 32.
#pragma unroll
  for (int ni = 0; ni < 2; ++ni) {
    float v = -3.402823466e38f;
#pragma unroll
    for (int mi = 0; mi < 4; ++mi)
#pragma unroll
      for (int reg = 0; reg < 16; ++reg) v = fmaxf(v, acc[mi][ni][reg]);
    v = fmaxf(v, __shfl_xor(v, 32, 64));
    if (half == 0) {
      const int gcol = bn * TNB + wave * 64 + ni * 32 + l32;
      atomicMax(&colmax[gcol], fenc(v));
    }
  }
}

__global__ __launch_bounds__(1024) void finalize_kernel(
    const int* __restrict__ rowmax, const int* __restrict__ colmax,
    float* __restrict__ out) {
  const int tid = threadIdx.x;
  float s1 = 0.f, s2 = 0.f;
  for (int i = tid; i < N_ROWS; i += 1024) {
    s1 += 1.0f - fdec(rowmax[i]);
    s2 += 1.0f - fdec(colmax[i]);
  }
#pragma unroll
  for (int off = 32; off > 0; off >>= 1) {
    s1 += __shfl_down(s1, off, 64);
    s2 += __shfl_down(s2, off, 64);
  }
  __shared__ float r1[16], r2[16];
  if ((tid & 63) == 0) {
    r1[tid >> 6] = s1;
    r2[tid >> 6] = s2;
  }
  __syncthreads();
  if (tid == 0) {
    const double SIGMA = 0.3;
    const double H_CONST = 0.5 * log(2.0 * 3.14159265358979323846 * SIGMA * SIGMA) + 0.5;
    const float HS = (float)(H_CONST / SIGMA);
    float a1 = 0.f, a2 = 0.f;
#pragma unroll
    for (int w = 0; w < 16; ++w) {
      a1 += r1[w];
      a2 += r2[w];
    }
    out[0] = HS * a1;
    out[1] = HS * a2;
  }
}

extern "C" void kernel_launch(void* const* d_in, const int* in_sizes, int n_in,
                              void* d_out, int out_size, void* d_ws, size_t ws_size,
                              hipStream_t stream) {
  const float* ex = (const float*)d_in[0];
  const float* ey = (const float*)d_in[1];
  float* out = (float*)d_out;
  char* ws = (char*)d_ws;

  unsigned char* exn = (unsigned char*)ws;                                   // 8 MB
  unsigned char* eyn = (unsigned char*)(ws + (size_t)N_ROWS * KDIM);         // 8 MB
  int* rowmax = (int*)(ws + (size_t)N_ROWS * KDIM * 2);                      // 32 KB
  int* colmax = rowmax + N_ROWS;                                             // 32 KB

  normalize_kernel<<<2 * N_ROWS / 4, 256, 0, stream>>>(ex, ey, exn, eyn, rowmax, colmax);
  gemm_max_kernel<<<dim3(64, 32), 256, 0, stream>>>(exn, eyn, rowmax, colmax);
  finalize_kernel<<<1, 1024, 0, stream>>>(rowmax, colmax, out);
}

// Round 11
// 201.408 us; speedup vs baseline: 1.4337x; 1.0747x over previous
//
#include <hip/hip_runtime.h>
#include <math.h>

typedef int intx4 __attribute__((ext_vector_type(4)));
typedef int intx8 __attribute__((ext_vector_type(8)));
typedef float floatx16 __attribute__((ext_vector_type(16)));

#define N_ROWS 8192
#define KDIM 1024

// E8M0 scale bytes: 123 -> 2^-4 per side (data pre-scaled by 2^4 each side)
#define SCALE_WORD 0x7B7B7B7B

// order-preserving float->int encoding for atomicMax
__device__ __forceinline__ int fenc(float f) {
  int i = __float_as_int(f);
  return i >= 0 ? i : (i ^ 0x7fffffff);
}
__device__ __forceinline__ float fdec(int e) {
  int b = e >= 0 ? e : (e ^ 0x7fffffff);
  return __int_as_float(b);
}

// One WAVE per row (4 rows/block, no __syncthreads): computes 1/||x|| (fp32),
// writes row normalized*16 as e4m3 via HW cvt, inits the max slot.
__global__ __launch_bounds__(256) void normalize_kernel(
    const float* __restrict__ ex, const float* __restrict__ ey,
    unsigned char* __restrict__ exn, unsigned char* __restrict__ eyn,
    int* __restrict__ rowmax, int* __restrict__ colmax) {
  const int wave = threadIdx.x >> 6, lane = threadIdx.x & 63;
  const int gr = blockIdx.x * 4 + wave;  // 0..16383
  const float* x;
  unsigned char* out;
  int* mslot;
  int row;
  if (gr < N_ROWS) {
    x = ex; out = exn; mslot = rowmax; row = gr;
  } else {
    x = ey; out = eyn; mslot = colmax; row = gr - N_ROWS;
  }
  const float4* xr = (const float4*)(x + (size_t)row * KDIM);
  float4 v[4];
  float ss = 0.f;
#pragma unroll
  for (int j = 0; j < 4; ++j) {
    v[j] = xr[lane + j * 64];  // coalesced
    ss += v[j].x * v[j].x + v[j].y * v[j].y + v[j].z * v[j].z + v[j].w * v[j].w;
  }
#pragma unroll
  for (int off = 32; off > 0; off >>= 1) ss += __shfl_xor(ss, off, 64);
  const float rs = 16.0f * rsqrtf(fmaxf(ss, 1e-24f));  // 2^4 pre-scale
  int* op = (int*)(out + (size_t)row * KDIM);
#pragma unroll
  for (int j = 0; j < 4; ++j) {
    int w = __builtin_amdgcn_cvt_pk_fp8_f32(v[j].x * rs, v[j].y * rs, 0, false);
    w = __builtin_amdgcn_cvt_pk_fp8_f32(v[j].z * rs, v[j].w * rs, w, true);
    op[lane + j * 64] = w;
  }
  if (lane == 0) mslot[row] = (int)0x80000000;  // encoded -inf floor
}

// 128x128 tile GEMM (A @ B^T, row-major K-contiguous e4m3) using MX-scaled
// mfma_scale_f32_32x32x64_f8f6f4, fused with row/col max reduction.
//
// Round-11 change: __launch_bounds__(256, 4) on the r8 kernel (its best
// sibling: 136 total regs -> 3 waves/SIMD, 32 KB LDS). Cross-round analysis
// (r6 121 / r8 131 / r10 136 us, all ~2x their pipe-demand floor) says the
// plateau is latency at 2-3 deep block overlap, not LDS throughput or tile
// shape. 4 blocks/CU needs total <= 128 regs: acc[2][2]=64 + arch <= 64.
// bF is made transient (ni-outer) to free the ~8 regs r8 was over.
// Spill tripwire: WRITE_SIZE (clean ~18 MB; r4's true spill was ~1 GB).
//
// Pipeline (verified r6/r8 shape): buffer_load->VGPR->ds_write; only vmcnt
// wait is the ds_write data dependence, placed AFTER compute:
//   LOAD(s+1); COMPUTE(buf s&1); WRITE(buf (s+1)&1); barrier
//
// LDS swizzle (verified r8): 64-B rows, 16-B chunk c of row r at slot
// c ^ ((r>>1)&3) -> bank-group 4*(r&1) + slot covers all 8 groups x 2 lanes
// per quarter-wave. Fragment reads recover true chunk 2h+j, so operand bytes
// at (half,j,b) equal global k = k0+(2h+j)*16+b for BOTH A and B -> exact
// dot-product pairing (absmax 0.0 through r10).
__global__ __launch_bounds__(256, 4) void gemm_max_kernel(
    const unsigned char* __restrict__ A, const unsigned char* __restrict__ B,
    int* __restrict__ rowmax, int* __restrict__ colmax) {
  constexpr int TM = 128, BK = 64, K = KDIM;
  constexpr int BUF = TM * BK;                          // 8 KB per buffer
  __shared__ __align__(16) unsigned char sA[2 * BUF];   // 16 KB
  __shared__ __align__(16) unsigned char sB[2 * BUF];   // 16 KB

  const int bm = blockIdx.x, bn = blockIdx.y;
  const int tid = threadIdx.x;
  const int lane = tid & 63, wave = tid >> 6;
  const int wm = wave >> 1, wn = wave & 1;  // 2x2 waves of 64x64
  const int l32 = lane & 31, half = lane >> 5;
  const int fsw = (l32 >> 1) & 3;                 // f(row) = (row>>1)&3
  const int oLo = (((2 * half + 0) ^ fsw) << 4);  // swizzled slot offsets
  const int oHi = (((2 * half + 1) ^ fsw) << 4);

  const char* Ab = (const char*)(A + (size_t)bm * TM * K);
  const char* Bb = (const char*)(B + (size_t)bn * TM * K);

  floatx16 acc[2][2] = {};

  // Staging: wave w stages rows w*32..+31 of each tile per step.
  // Dest (linear lane*16): row r_d = wave*32 + (lane>>2), slot lane&3.
  // Source chunk = (lane&3) ^ f(r_d) = (lane&3) ^ ((lane>>3)&3); the +16-row
  // second write keeps the same offset (f(r+16)==f(r)).
  const int src_c16 = (((lane & 3) ^ ((lane >> 3) & 3)) << 4);
  const char* gA = Ab + (size_t)(wave * 32 + (lane >> 2)) * K + src_c16;
  const char* gB = Bb + (size_t)(wave * 32 + (lane >> 2)) * K + src_c16;
  unsigned char* wA = sA + wave * 2048 + lane * 16;  // linear dest (+buf,+it*1024)
  unsigned char* wB = sB + wave * 2048 + lane * 16;

  intx4 pf[4];  // prefetch regs: 2 A-chunks + 2 B-chunks (16 VGPRs)

#define LOADT(k0)                                            \
  do {                                                       \
    pf[0] = *(const intx4*)(gA + (size_t)(k0));              \
    pf[1] = *(const intx4*)(gA + (size_t)(k0) + 16 * K);     \
    pf[2] = *(const intx4*)(gB + (size_t)(k0));              \
    pf[3] = *(const intx4*)(gB + (size_t)(k0) + 16 * K);     \
  } while (0)

#define WRITET(buf)                                          \
  do {                                                       \
    *(intx4*)(wA + (buf)*BUF) = pf[0];                       \
    *(intx4*)(wA + (buf)*BUF + 1024) = pf[1];                \
    *(intx4*)(wB + (buf)*BUF) = pf[2];                       \
    *(intx4*)(wB + (buf)*BUF + 1024) = pf[3];                \
  } while (0)

#define COMPUTE(cur)                                                        \
  do {                                                                      \
    intx8 aF[2];                                                            \
    _Pragma("unroll") for (int mi = 0; mi < 2; ++mi) {                      \
      const unsigned char* aBase =                                          \
          &sA[(cur)*BUF + (wm * 64 + mi * 32 + l32) * BK];                  \
      const intx4 lo = *(const intx4*)(aBase + oLo);                        \
      const intx4 hi = *(const intx4*)(aBase + oHi);                        \
      aF[mi] = __builtin_shufflevector(lo, hi, 0, 1, 2, 3, 4, 5, 6, 7);     \
    }                                                                       \
    _Pragma("unroll") for (int ni = 0; ni < 2; ++ni) {                      \
      const unsigned char* bBase =                                          \
          &sB[(cur)*BUF + (wn * 64 + ni * 32 + l32) * BK];                  \
      const intx4 lo = *(const intx4*)(bBase + oLo);                        \
      const intx4 hi = *(const intx4*)(bBase + oHi);                        \
      const intx8 bF =                                                      \
          __builtin_shufflevector(lo, hi, 0, 1, 2, 3, 4, 5, 6, 7);          \
      _Pragma("unroll") for (int mi = 0; mi < 2; ++mi)                      \
          acc[mi][ni] = __builtin_amdgcn_mfma_scale_f32_32x32x64_f8f6f4(    \
              aF[mi], bF, acc[mi][ni], 0, 0, 0, SCALE_WORD, 0,              \
              SCALE_WORD);                                                  \
    }                                                                       \
  } while (0)

  LOADT(0);
  WRITET(0);
  __syncthreads();

  // unroll 1: keeps one pf set live (full unroll would hoist all -> spill)
#pragma unroll 1
  for (int step = 0; step < K / BK - 1; ++step) {
    LOADT((step + 1) * BK);   // in flight across the whole compute phase
    COMPUTE(step & 1);
    WRITET((step + 1) & 1);   // vmcnt wait is data-dependent, post-compute
    __syncthreads();
  }
  COMPUTE((K / BK - 1) & 1);

#undef LOADT
#undef WRITET
#undef COMPUTE

  // 32x32 C/D layout (m74/m101, dtype-independent):
  //   col = lane&31, row = (reg&3) + 8*(reg>>2) + 4*(lane>>5), reg in [0,16)
  // Row maxes: in-lane over ni, shuffle across 32 cols (masks 1..16 stay
  // within a half), l32==0 lanes write.
#pragma unroll
  for (int mi = 0; mi < 2; ++mi) {
#pragma unroll
    for (int reg = 0; reg < 16; ++reg) {
      float v = fmaxf(acc[mi][0][reg], acc[mi][1][reg]);
#pragma unroll
      for (int m = 1; m < 32; m <<= 1) v = fmaxf(v, __shfl_xor(v, m, 64));
      if (l32 == 0) {
        const int grow = bm * TM + wm * 64 + mi * 32 +
                         (reg & 3) + 8 * (reg >> 2) + 4 * half;
        atomicMax(&rowmax[grow], fenc(v));
      }
    }
  }
  // Col maxes: in-lane over mi,reg (32 vals), combine halves via xor 32.
#pragma unroll
  for (int ni = 0; ni < 2; ++ni) {
    float v = -3.402823466e38f;
#pragma unroll
    for (int mi = 0; mi < 2; ++mi)
#pragma unroll
      for (int reg = 0; reg < 16; ++reg) v = fmaxf(v, acc[mi][ni][reg]);
    v = fmaxf(v, __shfl_xor(v, 32, 64));
    if (half == 0) {
      const int gcol = bn * TM + wn * 64 + ni * 32 + l32;
      atomicMax(&colmax[gcol], fenc(v));
    }
  }
}

__global__ __launch_bounds__(1024) void finalize_kernel(
    const int* __restrict__ rowmax, const int* __restrict__ colmax,
    float* __restrict__ out) {
  const int tid = threadIdx.x;
  float s1 = 0.f, s2 = 0.f;
  for (int i = tid; i < N_ROWS; i += 1024) {
    s1 += 1.0f - fdec(rowmax[i]);
    s2 += 1.0f - fdec(colmax[i]);
  }
#pragma unroll
  for (int off = 32; off > 0; off >>= 1) {
    s1 += __shfl_down(s1, off, 64);
    s2 += __shfl_down(s2, off, 64);
  }
  __shared__ float r1[16], r2[16];
  if ((tid & 63) == 0) {
    r1[tid >> 6] = s1;
    r2[tid >> 6] = s2;
  }
  __syncthreads();
  if (tid == 0) {
    const double SIGMA = 0.3;
    const double H_CONST = 0.5 * log(2.0 * 3.14159265358979323846 * SIGMA * SIGMA) + 0.5;
    const float HS = (float)(H_CONST / SIGMA);
    float a1 = 0.f, a2 = 0.f;
#pragma unroll
    for (int w = 0; w < 16; ++w) {
      a1 += r1[w];
      a2 += r2[w];
    }
    out[0] = HS * a1;
    out[1] = HS * a2;
  }
}

extern "C" void kernel_launch(void* const* d_in, const int* in_sizes, int n_in,
                              void* d_out, int out_size, void* d_ws, size_t ws_size,
                              hipStream_t stream) {
  const float* ex = (const float*)d_in[0];
  const float* ey = (const float*)d_in[1];
  float* out = (float*)d_out;
  char* ws = (char*)d_ws;

  unsigned char* exn = (unsigned char*)ws;                                   // 8 MB
  unsigned char* eyn = (unsigned char*)(ws + (size_t)N_ROWS * KDIM);         // 8 MB
  int* rowmax = (int*)(ws + (size_t)N_ROWS * KDIM * 2);                      // 32 KB
  int* colmax = rowmax + N_ROWS;                                             // 32 KB

  normalize_kernel<<<2 * N_ROWS / 4, 256, 0, stream>>>(ex, ey, exn, eyn, rowmax, colmax);
  gemm_max_kernel<<<dim3(64, 64), 256, 0, stream>>>(exn, eyn, rowmax, colmax);
  finalize_kernel<<<1, 1024, 0, stream>>>(rowmax, colmax, out);
}